// Round 16
// baseline (629.200 us; speedup 1.0000x reference)
//
#include <hip/hip_runtime.h>

typedef short v8s __attribute__((ext_vector_type(8)));
typedef short v4s __attribute__((ext_vector_type(4)));
typedef float v4f __attribute__((ext_vector_type(4)));

#define BN 128
#define BK 64

__device__ __forceinline__ float b2f(unsigned short u) {
    union { unsigned int i; float f; } x; x.i = ((unsigned int)u) << 16; return x.f;
}
__device__ __forceinline__ unsigned short f2b(float f) {
    union { float f; unsigned int i; } x; x.f = f;
    unsigned int r = x.i + 0x7fffu + ((x.i >> 16) & 1u);
    return (unsigned short)(r >> 16);
}

// async global->LDS, 16B per lane. LDS dest is wave-uniform base + lane*16,
// so LDS layout is linear; swizzle is applied on the GLOBAL source address.
__device__ __forceinline__ void gload16(const void* g, void* l) {
    __builtin_amdgcn_global_load_lds(
        (const __attribute__((address_space(1))) void*)g,
        (__attribute__((address_space(3))) void*)l, 16, 0, 0);
}

// Shared MFMA GEMM body, 256x128 tile, 512 threads (8 waves, 4x2 wave grid).
// COUNTED-VMCNT software pipeline (T4, m218): full A+B double-buffer (96KB,
// 1 block/CU x 8 waves). Per tile: s_waitcnt vmcnt(6) -> s_barrier -> compute
// -> s_barrier -> stage(t+2). Never vmcnt(0) in the loop (last tile only).
// EPI: 1 transposed bf16 store, COALESCED via 2-pass [64][264] LDS transpose
//      2 +bias_f32[gm] — COALESCED via 4-pass [64][132] f32 LDS
template<int EPI>
__device__ __forceinline__ void gemm_body(
    const unsigned short* __restrict__ A, int lda, long aOff,
    const unsigned short* __restrict__ BT, int ldb, long bOff,
    void* __restrict__ C, int ldc, long cOff, long cSBt,
    int K, const float* __restrict__ bias,
    const float* __restrict__ resid, int ldr,
    int bm, int bn)
{
    __shared__ unsigned short SM[49152];   // 96KB: 2 x (A 32KB | B 16KB)

    const int tid = threadIdx.x;           // 512 threads
    const int wave = tid >> 6, lane = tid & 63;
    const int wm = (wave >> 1) * 64, wn = (wave & 1) * 64;
    const int quad = lane >> 4, l16 = lane & 15;
    const int sx = l16 & 7;

    const unsigned short* aP[4]; const unsigned short* bP[2];
    int aL[4], bL[2];
#pragma unroll
    for (int p = 0; p < 4; p++) {
        int idx = p * 512 + tid;            // A: 256 rows x 8 chunks
        int row = idx >> 3, c = idx & 7, cc = c ^ (row & 7);
        aP[p] = A + aOff + (long)(bm + row) * lda + cc * 8;
        aL[p] = idx * 8;
    }
#pragma unroll
    for (int p = 0; p < 2; p++) {
        int idx = p * 512 + tid;            // B: 128 rows x 8 chunks
        int row = idx >> 3, c = idx & 7, cc = c ^ (row & 7);
        bP[p] = BT + bOff + (long)(bn + row) * ldb + cc * 8;
        bL[p] = 16384 + idx * 8;
    }

    auto stage = [&](int t, int b) {
        const int k0 = t * BK;
        unsigned short* base = &SM[b * 24576];
#pragma unroll
        for (int p = 0; p < 4; p++) gload16(aP[p] + k0, base + aL[p]);
#pragma unroll
        for (int p = 0; p < 2; p++) gload16(bP[p] + k0, base + bL[p]);
    };

    v4f acc[4][4] = {};
    const int nt = K >> 6;

    stage(0, 0);
    stage(1, 1);

    for (int t = 0; t < nt; t++) {
        if (t + 1 < nt) asm volatile("s_waitcnt vmcnt(6)" ::: "memory");
        else            asm volatile("s_waitcnt vmcnt(0)" ::: "memory");
        __builtin_amdgcn_s_barrier();
        __builtin_amdgcn_sched_barrier(0);
        const unsigned short* As = &SM[(t & 1) * 24576];
        const unsigned short* Bs = As + 16384;
#pragma unroll
        for (int ks = 0; ks < 2; ks++) {
            v8s af[4], bf[4];
#pragma unroll
            for (int i = 0; i < 4; i++) {
                const int co = ((ks * 4 + quad) ^ sx) * 8;
                af[i] = *(const v8s*)&As[(wm + i * 16 + l16) * 64 + co];
                bf[i] = *(const v8s*)&Bs[(wn + i * 16 + l16) * 64 + co];
            }
#pragma unroll
            for (int i = 0; i < 4; i++)
#pragma unroll
                for (int j = 0; j < 4; j++)
                    acc[i][j] = __builtin_amdgcn_mfma_f32_16x16x32_bf16(af[i], bf[j], acc[i][j], 0, 0, 0);
        }
        __builtin_amdgcn_s_barrier();
        __builtin_amdgcn_sched_barrier(0);
        if (t + 2 < nt) stage(t + 2, t & 1);
    }

    if (EPI == 1) {
        // Transposed store: 2 passes of 64 n-rows through SM [64][264].
        const int bb = bm >> 9, mm0 = bm & 511;
        unsigned short* Cu = (unsigned short*)C + cOff + (long)bb * cSBt + mm0;
#pragma unroll
        for (int pass = 0; pass < 2; pass++) {
            __syncthreads();
            if ((wave & 1) == pass) {
#pragma unroll
                for (int i = 0; i < 4; i++) {
                    int mb = wm + i * 16 + quad * 4;
#pragma unroll
                    for (int j = 0; j < 4; j++) {
                        int n = j * 16 + l16;
                        unsigned int lo = (unsigned int)f2b(acc[i][j][0]) | ((unsigned int)f2b(acc[i][j][1]) << 16);
                        unsigned int hi = (unsigned int)f2b(acc[i][j][2]) | ((unsigned int)f2b(acc[i][j][3]) << 16);
                        *(unsigned int*)&SM[n * 264 + mb] = lo;
                        *(unsigned int*)&SM[n * 264 + mb + 2] = hi;
                    }
                }
            }
            __syncthreads();
            int row = tid >> 3, part = tid & 7;
            const uint4* s = (const uint4*)&SM[row * 264 + part * 32];
            uint4 v0 = s[0], v1 = s[1];
            uint4* d = (uint4*)&Cu[(long)(bn + pass * 64 + row) * ldc + part * 32];
            d[0] = v0; d[1] = v1;
        }
    } else {
        // Row-major store: 4 passes of 64 m-rows through f32 LDS [64][132].
        float* TF = (float*)SM;
        unsigned short* Cu = (unsigned short*)C + cOff;
#pragma unroll
        for (int pass = 0; pass < 4; pass++) {
            __syncthreads();
            if ((wave >> 1) == pass) {
#pragma unroll
                for (int i = 0; i < 4; i++) {
                    int rl = i * 16 + quad * 4;
#pragma unroll
                    for (int j = 0; j < 4; j++) {
                        int cl = wn + j * 16 + l16;
#pragma unroll
                        for (int r = 0; r < 4; r++)
                            TF[(rl + r) * 132 + cl] = acc[i][j][r];
                    }
                }
            }
            __syncthreads();
            int row = tid >> 3, part = tid & 7;
            int gm = bm + pass * 64 + row;
            const float* srcr = &TF[row * 132 + part * 16];
            float bs = (EPI == 2) ? bias[gm] : 0.f;
            const float* rr = (EPI == 4) ? &resid[(long)gm * ldr + bn + part * 16] : nullptr;
            unsigned short tmp[16];
#pragma unroll
            for (int e = 0; e < 16; e++) {
                float v = srcr[e];
                if (EPI == 2) v += bs;
                else v += rr[e];
                tmp[e] = f2b(v);
            }
            uint4* d = (uint4*)&Cu[(long)gm * ldc + bn + part * 16];
            d[0] = *(uint4*)&tmp[0];
            d[1] = *(uint4*)&tmp[8];
        }
    }
}

// merged q/k/v projections, flat 1024 blocks, XCD-swizzled (T1)
__global__ __launch_bounds__(512)
void proj3_k(const unsigned short* __restrict__ qb, const unsigned short* __restrict__ kb,
             const unsigned short* __restrict__ vb,
             const unsigned short* __restrict__ WqT, const unsigned short* __restrict__ WkT,
             const unsigned short* __restrict__ WvT,
             unsigned short* __restrict__ q1t, unsigned short* __restrict__ k1t,
             unsigned short* __restrict__ v1t)
{
    const int id = blockIdx.x;
    const int logical = (id & 7) * 128 + (id >> 3);
    if (logical < 256) {
        const int y = logical >> 2, x = logical & 3;
        gemm_body<1>(qb, 768, 0, WqT, 768, 0, q1t, 512, 0, 262144, 768,
                     nullptr, nullptr, 0, y * 256, x * BN);
    } else if (logical < 512) {
        const int l = logical - 256;
        const int y = l >> 2, x = l & 3;
        gemm_body<1>(kb, 768, 0, WkT, 768, 0, k1t, 512, 0, 262144, 768,
                     nullptr, nullptr, 0, y * 256, x * BN);
    } else {
        const int l = logical - 512;
        const int y = l >> 3, x = l & 7;
        gemm_body<1>(vb, 768, 0, WvT, 768, 0, v1t, 512, 0, 524288, 768,
                     nullptr, nullptr, 0, y * 256, x * BN);
    }
}

// merged conv-q / conv-k, flat 512 blocks, XCD-swizzled (T1)
__global__ __launch_bounds__(512)
void conv2_k(const unsigned short* __restrict__ Wconv_b,
             const unsigned short* __restrict__ q1t, const unsigned short* __restrict__ k1t,
             unsigned short* __restrict__ q1c, unsigned short* __restrict__ k1c,
             const float* __restrict__ bconv)
{
    const int id = blockIdx.x;
    const int logical = (id & 7) * 64 + (id >> 3);
    const int grp = logical >> 3;
    const int t = logical & 7;
    const int b = grp & 31, sel = grp >> 5;
    const int bm = (t >> 2) * 256, bn = (t & 3) * BN;
    const unsigned short* Bt = sel ? k1t : q1t;
    unsigned short* Cc = sel ? k1c : q1c;
    gemm_body<2>(Wconv_b, 512, 0, Bt, 512, (long)b * 262144,
                 Cc, 512, (long)b * 262144, 0, 512, bconv, nullptr, 0, bm, bn);
}

// FUSED FC + residual + LayerNorm + nan->0, writing final f32 out directly.
__global__ __launch_bounds__(512)
void fc_ln_k(const unsigned short* __restrict__ out1,  // (16384,1024) bf16
             const unsigned short* __restrict__ WfcT,  // (768,1024) bf16
             const float* __restrict__ resid,          // (16384,768) f32
             const float* __restrict__ gamma,
             const float* __restrict__ beta,
             float* __restrict__ out)                  // (16384,768) f32
{
    __shared__ unsigned short SM[53248];   // 104KB: A 8KB | B 96KB

    const int tid = threadIdx.x;
    const int wave = tid >> 6, lane = tid & 63;
    const int quad = lane >> 4, l16 = lane & 15;
    const int sx = l16 & 7;
    const int bm = blockIdx.x * 64;
    const int wn = wave * 96;

    const int arow = tid >> 3, ac = tid & 7;
    const unsigned short* aP = out1 + (long)(bm + arow) * 1024 + (ac ^ (arow & 7)) * 8;
    const int aL = tid * 8;

    v4f acc[4][6] = {};

    for (int k0 = 0; k0 < 1024; k0 += 64) {
        gload16(aP + k0, &SM[aL]);
#pragma unroll
        for (int p = 0; p < 12; p++) {
            int idx = p * 512 + tid;
            int row = idx >> 3, c = idx & 7, cc = c ^ (row & 7);
            gload16(WfcT + (long)row * 1024 + cc * 8 + k0, &SM[4096 + idx * 8]);
        }
        __syncthreads();
#pragma unroll
        for (int ks = 0; ks < 2; ks++) {
            const int co = ((ks * 4 + quad) ^ sx) * 8;
            v8s af[4], bf[6];
#pragma unroll
            for (int i = 0; i < 4; i++)
                af[i] = *(const v8s*)&SM[(i * 16 + l16) * 64 + co];
#pragma unroll
            for (int j = 0; j < 6; j++)
                bf[j] = *(const v8s*)&SM[4096 + (wn + j * 16 + l16) * 64 + co];
#pragma unroll
            for (int i = 0; i < 4; i++)
#pragma unroll
                for (int j = 0; j < 6; j++)
                    acc[i][j] = __builtin_amdgcn_mfma_f32_16x16x32_bf16(af[i], bf[j], acc[i][j], 0, 0, 0);
        }
        __syncthreads();
    }

    float g6[6], be6[6];
#pragma unroll
    for (int j = 0; j < 6; j++) {
        g6[j] = gamma[wn + j * 16 + l16];
        be6[j] = beta[wn + j * 16 + l16];
    }

    float rs[4][4] = {{0.f}}, rq[4][4] = {{0.f}};
#pragma unroll
    for (int i = 0; i < 4; i++)
#pragma unroll
        for (int r = 0; r < 4; r++) {
            int gm = bm + i * 16 + quad * 4 + r;
            const float* rr = &resid[(long)gm * 768 + wn + l16];
#pragma unroll
            for (int j = 0; j < 6; j++) {
                float v = acc[i][j][r] + rr[j * 16];
                acc[i][j][r] = v;
                rs[i][r] += v;
                rq[i][r] += v * v;
            }
        }
#pragma unroll
    for (int off = 1; off < 16; off <<= 1)
#pragma unroll
        for (int i = 0; i < 4; i++)
#pragma unroll
            for (int r = 0; r < 4; r++) {
                rs[i][r] += __shfl_xor(rs[i][r], off, 64);
                rq[i][r] += __shfl_xor(rq[i][r], off, 64);
            }

    float* ST = (float*)SM;
    if (l16 == 0) {
#pragma unroll
        for (int i = 0; i < 4; i++)
#pragma unroll
            for (int r = 0; r < 4; r++) {
                int row = i * 16 + quad * 4 + r;
                ST[row * 8 + wave] = rs[i][r];
                ST[512 + row * 8 + wave] = rq[i][r];
            }
    }
    __syncthreads();

    float mean[4][4], rstd[4][4];
#pragma unroll
    for (int i = 0; i < 4; i++)
#pragma unroll
        for (int r = 0; r < 4; r++) {
            int row = i * 16 + quad * 4 + r;
            float s = 0.f, s2 = 0.f;
#pragma unroll
            for (int w = 0; w < 8; w++) {
                s += ST[row * 8 + w];
                s2 += ST[512 + row * 8 + w];
            }
            float m = s * (1.0f / 768.0f);
            float var = s2 * (1.0f / 768.0f) - m * m;
            if (!(var >= 0.f)) var = 0.f;
            mean[i][r] = m;
            rstd[i][r] = rsqrtf(var + 1e-6f);
        }

#pragma unroll
    for (int i = 0; i < 4; i++)
#pragma unroll
        for (int r = 0; r < 4; r++) {
            int gm = bm + i * 16 + quad * 4 + r;
            float* orow = &out[(long)gm * 768 + wn + l16];
#pragma unroll
            for (int j = 0; j < 6; j++) {
                float o = (acc[i][j][r] - mean[i][r]) * rstd[i][r] * g6[j] + be6[j];
                union { float f; unsigned int u; } uu; uu.f = o;
                if ((uu.u & 0x7FFFFFFFu) > 0x7F800000u) uu.f = 0.f;
                orow[j * 16] = uu.f;
            }
        }
}

// Fused scores + mask + softmax + attn-write + PV, ZERO persistent score state.
// MAX-FREE softmax. Sweep 1: counted-vmcnt K pipeline (KA <-> VB[0:16KB]).
// Sweep 2 NOW ALSO counted-vmcnt: new 16KB K2 buffer (LDS 76KB, still 2
// blocks/CU at the 80KB budget) lets K alternate KA<->K2 one tile ahead:
// per tile stageV(kt) -> stageK(kt+1, alt) -> s_waitcnt vmcnt(2) (V[kt] and
// the strictly-older K[kt] retired; K[kt+1]'s 2 loads ride through both
// barriers) -> barrier -> compute -> barrier. The old __syncthreads drained
// all 6 just-issued loads; now only V's 4 are waited and K is pre-landed.
// T5 setprio wraps the MFMA clusters.
__global__ __launch_bounds__(512, 4)
void scores_pv_k(const unsigned short* __restrict__ q1c,
                 const unsigned short* __restrict__ k1c,
                 const unsigned short* __restrict__ v1t,
                 float* __restrict__ attn,
                 unsigned short* __restrict__ out1,
                 const int* __restrict__ mask1,
                 const int* __restrict__ mask2,
                 float scale)
{
    // XCD-aware swizzle: 1024 blocks = 256 (b,h) x 4 q-chunks.
    const int id = blockIdx.x;
    const int logical = (id & 7) * 128 + (id >> 3);
    const int z = logical >> 2;
    const int bx = logical & 3;
    const int b = z >> 3, h = z & 7;

    const unsigned short* Qb = q1c + (long)b * 262144 + h * 64;
    const unsigned short* Kb = k1c + (long)b * 262144 + h * 64;
    const unsigned short* Vb = v1t + (long)b * 524288 + (long)h * 65536;

    __shared__ unsigned short KA[128 * 64];    // 16KB: K tile
    __shared__ unsigned short K2[128 * 64];    // 16KB: alternate K tile (sweep 2)
    __shared__ unsigned short VB[128 * 128];   // 32KB: V tile; first 16KB = K buf in sweep 1
    __shared__ unsigned short Pl[8][640];      // 10KB
    __shared__ int m2s[512];                   // 2KB    -> 76KB total

    const int tid = threadIdx.x;
    const int wave = tid >> 6, lane = tid & 63;
    const int quad = lane >> 4, l16 = lane & 15;
    const int sx = l16 & 7;
    const int bm = bx * 128;
    const int row_l = wave * 16 + l16;
    const int qrow = bm + row_l;

    auto stageK = [&](int kt, unsigned short* dst) {
#pragma unroll
        for (int p = 0; p < 2; p++) {
            int idx = p * 512 + tid;
            int row = idx >> 3, c = idx & 7, cc = c ^ (row & 7);
            gload16(Kb + (long)(kt * 128 + row) * 512 + cc * 8, &dst[idx * 8]);
        }
    };
    auto stageV = [&](int kt) {
#pragma unroll
        for (int p = 0; p < 4; p++) {
            int idx = p * 512 + tid;
            int dv = idx >> 4, c = idx & 15, cc = c ^ (dv & 7);
            gload16(Vb + (long)dv * 512 + kt * 128 + cc * 8, &VB[idx * 8]);
        }
    };

    // ---- prologue: reg loads FIRST (older than staged tiles for vmcnt
    // counting), then the two K prefetches.
    v8s qf0 = *(const v8s*)&Qb[(long)qrow * 512 + quad * 8];
    v8s qf1 = *(const v8s*)&Qb[(long)qrow * 512 + 32 + quad * 8];
    const int m1 = mask1[b * 512 + qrow];
    m2s[tid] = mask2[b * 512 + tid];
    __builtin_amdgcn_sched_barrier(0);
    stageK(0, KA);
    stageK(1, &VB[0]);
    // m2s visibility WITHOUT draining vmcnt
    asm volatile("s_waitcnt lgkmcnt(0)" ::: "memory");
    __builtin_amdgcn_s_barrier();
    __builtin_amdgcn_sched_barrier(0);

    float sum = 0.f;

    // ---- sweep 1: softmax denominator (max-free), counted-vmcnt pipeline
    for (int kt = 0; kt < 4; kt++) {
        const unsigned short* cur = (kt & 1) ? &VB[0] : KA;
        asm volatile("s_waitcnt vmcnt(2)" ::: "memory");
        __builtin_amdgcn_s_barrier();
        __builtin_amdgcn_sched_barrier(0);
        __builtin_amdgcn_s_setprio(1);
#pragma unroll
        for (int jl = 0; jl < 8; jl++) {
            const unsigned short* kr = &cur[(jl * 16 + l16) * 64];
            v8s kf0 = *(const v8s*)&kr[(quad ^ sx) << 3];
            v8s kf1 = *(const v8s*)&kr[((4 + quad) ^ sx) << 3];
            v4f a = (v4f){0.f, 0.f, 0.f, 0.f};
            a = __builtin_amdgcn_mfma_f32_16x16x32_bf16(kf0, qf0, a, 0, 0, 0);
            a = __builtin_amdgcn_mfma_f32_16x16x32_bf16(kf1, qf1, a, 0, 0, 0);
            int j = kt * 8 + jl;
            int4 m2v = *(const int4*)&m2s[j * 16 + quad * 4];
            float s0 = (m1 != 0 || m2v.x != 0) ? 1e-9f : a[0] * scale;
            float s1 = (m1 != 0 || m2v.y != 0) ? 1e-9f : a[1] * scale;
            float s2 = (m1 != 0 || m2v.z != 0) ? 1e-9f : a[2] * scale;
            float s3 = (m1 != 0 || m2v.w != 0) ? 1e-9f : a[3] * scale;
            sum += (__expf(s0) + __expf(s1)) + (__expf(s2) + __expf(s3));
        }
        __builtin_amdgcn_s_setprio(0);
        __builtin_amdgcn_s_barrier();
        __builtin_amdgcn_sched_barrier(0);
        if (kt < 2)       stageK(kt + 2, (kt & 1) ? &VB[0] : KA);
        else if (kt == 2) stageK(0, KA);   // prefetch sweep-2's first K tile
    }
    sum += __shfl_xor(sum, 16, 64);
    sum += __shfl_xor(sum, 32, 64);
    const float inv = 1.0f / sum;

    // ---- sweep 2: recompute scores per tile, write attn, PV
    // K alternates KA (kt even) / K2 (kt odd), staged ONE TILE AHEAD;
    // per-tile wait covers only V's 4 loads (counted vmcnt, never a drain
    // of in-flight prefetches until the last tile).
    float* Arow = attn + (long)z * 262144 + (long)qrow * 512;
    unsigned short* Pw = &Pl[wave][l16 * 40];
    v4f acc2[8];
#pragma unroll
    for (int t = 0; t < 8; t++) acc2[t] = (v4f){0.f, 0.f, 0.f, 0.f};

    for (int kt = 0; kt < 4; kt++) {
        stageV(kt);                                        // 4 loads
        if (kt < 3) stageK(kt + 1, (kt & 1) ? KA : K2);    // 2 loads, one ahead
        // V[kt] + (older) K[kt] retired; K[kt+1] stays in flight
        if (kt < 3) asm volatile("s_waitcnt vmcnt(2)" ::: "memory");
        else        asm volatile("s_waitcnt vmcnt(0)" ::: "memory");
        __builtin_amdgcn_s_barrier();
        __builtin_amdgcn_sched_barrier(0);
        const unsigned short* Kc = (kt & 1) ? K2 : KA;

#pragma unroll
        for (int g = 0; g < 4; g++) {
            float p8[8];
#pragma unroll
            for (int t2 = 0; t2 < 2; t2++) {
                int jl = g * 2 + t2;
                const unsigned short* kr = &Kc[(jl * 16 + l16) * 64];
                v8s kf0 = *(const v8s*)&kr[(quad ^ sx) << 3];
                v8s kf1 = *(const v8s*)&kr[((4 + quad) ^ sx) << 3];
                v4f a = (v4f){0.f, 0.f, 0.f, 0.f};
                a = __builtin_amdgcn_mfma_f32_16x16x32_bf16(kf0, qf0, a, 0, 0, 0);
                a = __builtin_amdgcn_mfma_f32_16x16x32_bf16(kf1, qf1, a, 0, 0, 0);
                int j = kt * 8 + jl;
                int4 m2v = *(const int4*)&m2s[j * 16 + quad * 4];
                float s0 = (m1 != 0 || m2v.x != 0) ? 1e-9f : a[0] * scale;
                float s1 = (m1 != 0 || m2v.y != 0) ? 1e-9f : a[1] * scale;
                float s2 = (m1 != 0 || m2v.z != 0) ? 1e-9f : a[2] * scale;
                float s3 = (m1 != 0 || m2v.w != 0) ? 1e-9f : a[3] * scale;
                p8[t2 * 4 + 0] = __expf(s0) * inv;
                p8[t2 * 4 + 1] = __expf(s1) * inv;
                p8[t2 * 4 + 2] = __expf(s2) * inv;
                p8[t2 * 4 + 3] = __expf(s3) * inv;
            }
            int j0 = kt * 8 + g * 2;
            // Pw write first; attn stores cover the LDS RAW latency.
            uint2 pr0, pr1;
            pr0.x = (unsigned int)f2b(p8[0]) | ((unsigned int)f2b(p8[1]) << 16);
            pr0.y = (unsigned int)f2b(p8[2]) | ((unsigned int)f2b(p8[3]) << 16);
            pr1.x = (unsigned int)f2b(p8[4]) | ((unsigned int)f2b(p8[5]) << 16);
            pr1.y = (unsigned int)f2b(p8[6]) | ((unsigned int)f2b(p8[7]) << 16);
            *(uint2*)&Pw[quad * 4] = pr0;
            *(uint2*)&Pw[16 + quad * 4] = pr1;
            v4f w0; w0[0] = p8[0]; w0[1] = p8[1]; w0[2] = p8[2]; w0[3] = p8[3];
            v4f w1; w1[0] = p8[4]; w1[1] = p8[5]; w1[2] = p8[6]; w1[3] = p8[7];
            __builtin_nontemporal_store(w0, (v4f*)&Arow[j0 * 16 + quad * 4]);
            __builtin_nontemporal_store(w1, (v4f*)&Arow[(j0 + 1) * 16 + quad * 4]);
            v8s pf = *(const v8s*)&Pw[quad * 8];
            __builtin_amdgcn_s_setprio(1);
#pragma unroll
            for (int t = 0; t < 8; t++) {
                v8s vf = *(const v8s*)&VB[(t * 16 + l16) * 128 + (((g * 4 + quad) ^ sx) << 3)];
                acc2[t] = __builtin_amdgcn_mfma_f32_16x16x32_bf16(vf, pf, acc2[t], 0, 0, 0);
            }
            __builtin_amdgcn_s_setprio(0);
        }
        // all waves done with VB and Kc; safe to restage next iteration
        __builtin_amdgcn_s_barrier();
        __builtin_amdgcn_sched_barrier(0);
    }

    // out1[b][qrow][h*128 + dv]
    unsigned short* Orow = out1 + (long)b * 524288 + (long)qrow * 1024 + h * 128;
#pragma unroll
    for (int t = 0; t < 8; t++) {
        v4s o;
        o[0] = (short)f2b(acc2[t][0]); o[1] = (short)f2b(acc2[t][1]);
        o[2] = (short)f2b(acc2[t][2]); o[3] = (short)f2b(acc2[t][3]);
        *(v4s*)&Orow[t * 16 + quad * 4] = o;
    }
}

// all weight prep (4 transposes f32->bf16^T + Wconv cast) + q/k/v bf16 casts
__global__ __launch_bounds__(256)
void prep_k(const float* __restrict__ Wq, const float* __restrict__ Wk,
            const float* __restrict__ Wv, const float* __restrict__ Wfc,
            const float* __restrict__ Wconv,
            const float* __restrict__ qf, const float* __restrict__ kf,
            const float* __restrict__ vf,
            unsigned short* __restrict__ WqT, unsigned short* __restrict__ WkT,
            unsigned short* __restrict__ WvT, unsigned short* __restrict__ WfcT,
            unsigned short* __restrict__ Wconv_b,
            unsigned short* __restrict__ qb, unsigned short* __restrict__ kb,
            unsigned short* __restrict__ vb)
{
    __shared__ float t[32][33];
    int blk = blockIdx.x, tid = threadIdx.x;
    if (blk < 2304) {
        const float* src; unsigned short* dst; int K, N, local;
        if (blk < 384)       { src = Wq;  dst = WqT;  K = 768;  N = 512;  local = blk; }
        else if (blk < 768)  { src = Wk;  dst = WkT;  K = 768;  N = 512;  local = blk - 384; }
        else if (blk < 1536) { src = Wv;  dst = WvT;  K = 768;  N = 1024; local = blk - 768; }
        else                 { src = Wfc; dst = WfcT; K = 1024; N = 768;  local = blk - 1536; }
        int nb32 = N >> 5;
        int kb32 = (local / nb32) * 32, nb = (local % nb32) * 32;
        int tx = tid & 31, ty = tid >> 5;
#pragma unroll
        for (int i = 0; i < 32; i += 8)
            t[ty + i][tx] = src[(long)(kb32 + ty + i) * N + nb + tx];
        __syncthreads();
#pragma unroll
        for (int i = 0; i < 32; i += 8)
            dst[(long)(nb + ty + i) * K + kb32 + tx] = f2b(t[tx][ty + i]);
    } else if (blk < 3328) {
        int i = (blk - 2304) * 256 + tid;   // Wconv: 512*512 = 262144
        Wconv_b[i] = f2b(Wconv[i]);
    } else {
        long t0 = (long)(blk - 3328) * 4096 + (long)tid * 16;
        const float* src; unsigned short* dst; long i = t0;
        if (t0 < 12582912L)       { src = qf; dst = qb; }
        else if (t0 < 25165824L)  { src = kf; dst = kb; i = t0 - 12582912L; }
        else                      { src = vf; dst = vb; i = t0 - 25165824L; }
        v4f a = __builtin_nontemporal_load((const v4f*)&src[i]);
        v4f b4 = __builtin_nontemporal_load((const v4f*)&src[i + 4]);
        v4f c4 = __builtin_nontemporal_load((const v4f*)&src[i + 8]);
        v4f d4 = __builtin_nontemporal_load((const v4f*)&src[i + 12]);
        v8s r0, r1;
        r0[0] = (short)f2b(a[0]);  r0[1] = (short)f2b(a[1]);
        r0[2] = (short)f2b(a[2]);  r0[3] = (short)f2b(a[3]);
        r0[4] = (short)f2b(b4[0]); r0[5] = (short)f2b(b4[1]);
        r0[6] = (short)f2b(b4[2]); r0[7] = (short)f2b(b4[3]);
        r1[0] = (short)f2b(c4[0]); r1[1] = (short)f2b(c4[1]);
        r1[2] = (short)f2b(c4[2]); r1[3] = (short)f2b(c4[3]);
        r1[4] = (short)f2b(d4[0]); r1[5] = (short)f2b(d4[1]);
        r1[6] = (short)f2b(d4[2]); r1[7] = (short)f2b(d4[3]);
        *(v8s*)&dst[i] = r0;
        *(v8s*)&dst[i + 8] = r1;
    }
}

extern "C" void kernel_launch(void* const* d_in, const int* in_sizes, int n_in,
                              void* d_out, int out_size, void* d_ws, size_t ws_size,
                              hipStream_t stream)
{
    // B=32, L=512, D_EMB=768, D_K=512, D_V=1024, H=8 — all I/O float32
    const float* q     = (const float*)d_in[0];
    const float* k     = (const float*)d_in[1];
    const float* v     = (const float*)d_in[2];
    const float* Wq    = (const float*)d_in[3];
    const float* Wk    = (const float*)d_in[4];
    const float* Wv    = (const float*)d_in[5];
    const float* Wconv = (const float*)d_in[6];
    const float* bconv = (const float*)d_in[7];
    const float* Wfc   = (const float*)d_in[8];
    const float* gamma = (const float*)d_in[9];
    const float* beta  = (const float*)d_in[10];
    const int* mask1   = (const int*)d_in[11];
    const int* mask2   = (const int*)d_in[12];

    float* out  = (float*)d_out;               // (32,512,768) f32
    float* attn = out + 12582912;              // (32,8,512,512) f32

    // ws layout (ushort elems); harness ws is ~950MB, out1 at +72MB is safe.
    unsigned short* ws = (unsigned short*)d_ws;
    unsigned short* WqT     = ws;              // 512x768
    unsigned short* WkT     = ws + 393216;     // 512x768
    unsigned short* WvT     = ws + 786432;     // 1024x768
    unsigned short* WfcT    = ws + 1572864;    // 768x1024
    unsigned short* Wconv_b = ws + 2359296;    // 512x512
    unsigned short* q1c     = ws + 2621440;    // (32,512,512)
    unsigned short* k1c     = ws + 11010048;   // (32,512,512)
    unsigned short* v1t     = ws + 19398656;   // (32,1024,512)
    unsigned short* out1    = ws + 36175872;   // (32,512,1024) bf16 [.. 52953088)

    // scratch in d_out's attn region (268 MB) — all dead before scores_pv writes attn
    unsigned short* aScr = (unsigned short*)attn;
    unsigned short* q1t = aScr;                // (32,512,512) feature-major
    unsigned short* k1t = aScr + 8388608;      // (32,512,512)
    unsigned short* qb  = aScr + 16777216;     // (32,512,768) bf16 cast of q
    unsigned short* kb  = aScr + 29360128;     // bf16 cast of k
    unsigned short* vb  = aScr + 41943040;     // bf16 cast of v  [.. 54525952)

    // all weight prep + q/k/v bf16 casts in one dispatch
    prep_k<<<12544, 256, 0, stream>>>(Wq, Wk, Wv, Wfc, Wconv, q, k, v,
                                      WqT, WkT, WvT, WfcT, Wconv_b, qb, kb, vb);

    const float scale = 0.04419417382415922f;  // 1/sqrt(512)

    // q/k/v projections in ONE dispatch (256-row tiles, XCD-swizzled)
    proj3_k<<<1024, 512, 0, stream>>>(
        qb, kb, vb, WqT, WkT, WvT, q1t, k1t, v1t);

    // conv over seq axis for q and k in ONE dispatch (256-row tiles, XCD-swz)
    conv2_k<<<512, 512, 0, stream>>>(
        Wconv_b, q1t, k1t, q1c, k1c, bconv);

    // fused scores + mask + softmax + attn write + PV -> out1 bf16 (ws)
    scores_pv_k<<<1024, 512, 0, stream>>>(
        q1c, k1c, v1t, attn, out1, mask1, mask2, scale);

    // fused FC + residual + LayerNorm + nan->0 -> f32 d_out
    fc_ln_k<<<256, 512, 0, stream>>>(out1, WfcT, q, gamma, beta, out);
}